// Round 8
// baseline (1947.794 us; speedup 1.0000x reference)
//
#include <hip/hip_runtime.h>

#define BATCH   16
#define NPTS    8192
#define NCH     64
#define NPOINT  1024
#define NSAMPLE 32
#define R2      0.01f

// AMD-canonical wave64 max-reduction stage on a u64 key via DPP (VALU pipe,
// no ds_bpermute). After shr1/2/4/8 lane15/31/47/63 hold row maxes; bcast15
// then bcast31 funnel to lane 63. Invalid-source lanes keep `old` (own value,
// bound_ctrl=false) so the max is a no-op there.
#define DPP_RED_STAGE(CTRL)                                                   \
    {                                                                         \
        int lo = (int)(unsigned)(key & 0xffffffffull);                        \
        int hi = (int)(unsigned)(key >> 32);                                  \
        int mlo = __builtin_amdgcn_update_dpp(lo, lo, CTRL, 0xF, 0xF, false); \
        int mhi = __builtin_amdgcn_update_dpp(hi, hi, CTRL, 0xF, 0xF, false); \
        unsigned long long mk =                                               \
            ((unsigned long long)(unsigned)mhi << 32) | (unsigned)mlo;        \
        if (mk > key) key = mk;                                               \
    }

struct FpsShared {
    float pts[NPTS * 3];                    // 96 KB
    unsigned long long red[2][4];
    float ring_f[2][16][3];                 // parity-double-buffered publish ring
};

// ---------------------------------------------------------------------------
// Kernel 1: blocks 0..15 FPS (one per batch), rest transpose (B,C,N)->(B,N,C).
// FPS bit-exact vs numpy: dist = ((dx*dx + dy*dy) + dz*dz) with _rn intrinsics
// (no FMA contraction), argmax with first-index tie-break.
// ---------------------------------------------------------------------------
__global__ __launch_bounds__(256, 1) void fps_tr_kernel(const float* __restrict__ xyz,
                                                        float* __restrict__ new_xyz,
                                                        const float* __restrict__ feat,
                                                        float* __restrict__ feat_t) {
    __shared__ union { FpsShared fps; float tile[64][65]; } U;
    const int t = threadIdx.x;

    if (blockIdx.x >= BATCH) {
        // ---------------- transpose path ----------------
        const int bidx = blockIdx.x - BATCH;          // b * (NPTS/64) + ntile
        const int b  = bidx >> 7;
        const int n0 = (bidx & 127) << 6;
        const int i  = t & 63, c0 = t >> 6;
        const float* src = feat + (size_t)b * NCH * NPTS;
#pragma unroll
        for (int r = 0; r < 16; ++r) {
            int c = c0 + r * 4;
            U.tile[c][i] = src[(size_t)c * NPTS + n0 + i];
        }
        __syncthreads();
        const int cc = t & 63, i0 = t >> 6;
        float* dst = feat_t + ((size_t)b * NPTS + n0) * NCH;
#pragma unroll
        for (int r = 0; r < 16; ++r) {
            int ii = i0 + r * 4;
            dst[(size_t)ii * NCH + cc] = U.tile[cc][ii];
        }
        return;
    }

    // ---------------- FPS path ----------------
    const int b = blockIdx.x;
    const float* g = xyz + (size_t)b * NPTS * 3;
    for (int i = t; i < NPTS * 3; i += 256) U.fps.pts[i] = g[i];
    __syncthreads();

    float px[32], py[32], pz[32], dist[32];
#pragma unroll
    for (int k = 0; k < 32; ++k) {
        const int p = t + (k << 8);
        px[k] = U.fps.pts[3 * p + 0];
        py[k] = U.fps.pts[3 * p + 1];
        pz[k] = U.fps.pts[3 * p + 2];
        dist[k] = 1e10f;
    }

    float fx = U.fps.pts[0], fy = U.fps.pts[1], fz = U.fps.pts[2];
    const int wave = t >> 6;

    for (int it = 0; it < NPOINT; ++it) {
        const int rb = (it >> 4) & 1, sl = it & 15;
        if (t == 0) {   // LDS-only publish: no vmcnt drain at the barrier
            U.fps.ring_f[rb][sl][0] = fx;
            U.fps.ring_f[rb][sl][1] = fy;
            U.fps.ring_f[rb][sl][2] = fz;
        }
        // update min-dists, track lane-local argmax (first-index tie-break)
        float bestv = -1.0f; int bestk = 0;
#pragma unroll
        for (int k = 0; k < 32; ++k) {
            float dx = __fsub_rn(px[k], fx);
            float dy = __fsub_rn(py[k], fy);
            float dz = __fsub_rn(pz[k], fz);
            float d  = __fadd_rn(__fadd_rn(__fmul_rn(dx, dx), __fmul_rn(dy, dy)),
                                 __fmul_rn(dz, dz));
            float nd = fminf(dist[k], d);
            dist[k] = nd;
            if (nd > bestv) { bestv = nd; bestk = k; }   // ascending k => first index wins
        }
        const int besti = t + (bestk << 8);
        // key: max value, then min index (dist >= 0 so float bits are monotonic)
        unsigned long long key =
            ((unsigned long long)__float_as_uint(bestv) << 32) | (unsigned)(~besti);
        DPP_RED_STAGE(0x111)   // row_shr:1
        DPP_RED_STAGE(0x112)   // row_shr:2
        DPP_RED_STAGE(0x114)   // row_shr:4
        DPP_RED_STAGE(0x118)   // row_shr:8  -> lane 15/31/47/63 = row max
        DPP_RED_STAGE(0x142)   // row_bcast15
        DPP_RED_STAGE(0x143)   // row_bcast31 -> lane 63 = wave max
        const int par = it & 1;
        if ((t & 63) == 63) U.fps.red[par][wave] = key;
        __syncthreads();

        if ((it & 15) == 15 && t < 48) {   // flush the completed 16-slot group
            const int base0 = b * NPOINT + (it & ~15);
            new_xyz[(size_t)(base0 + t / 3) * 3 + (t % 3)] =
                U.fps.ring_f[rb][t / 3][t % 3];
        }

        unsigned long long kk = U.fps.red[par][0];
        unsigned long long k1 = U.fps.red[par][1];
        unsigned long long k2 = U.fps.red[par][2];
        unsigned long long k3 = U.fps.red[par][3];
        if (k1 > kk) kk = k1;
        if (k2 > kk) kk = k2;
        if (k3 > kk) kk = k3;
        const int far = (int)(~(unsigned)kk);
        fx = U.fps.pts[3 * far + 0];
        fy = U.fps.pts[3 * far + 1];
        fz = U.fps.pts[3 * far + 2];
    }
}

// ---------------------------------------------------------------------------
// Kernel 2: fused ball-query + MLP + maxpool, one block per 8 centers.
// BQ: verified wave-scan code (gidx in LDS). MLP: verified round-2 LDS-weight
// code, with all three weight matrices staged once up front (~67 KB LDS).
// ---------------------------------------------------------------------------
struct BqShared {
    float w1[64 * 68];       // W1 rows padded to 68 (col 67 = 0)
    float w2[64 * 64];
    float w3[128 * 64];
    float b1s[64], b2s[64], b3s[128];
    float cxyz[8][3];
    int   gidx[8][NSAMPLE];
};

__global__ __launch_bounds__(256) void bq_mlp_kernel(const float* __restrict__ xyz,
                                                     const float* __restrict__ feat_t,
                                                     const float* __restrict__ new_xyz,
                                                     const float* __restrict__ W1,
                                                     const float* __restrict__ b1,
                                                     const float* __restrict__ W2,
                                                     const float* __restrict__ b2,
                                                     const float* __restrict__ W3,
                                                     const float* __restrict__ b3,
                                                     float* __restrict__ out_feat) {
    __shared__ BqShared S;
    const int t = threadIdx.x;
    const int b  = blockIdx.x >> 7;            // 128 blocks per batch
    const int p0 = (blockIdx.x & 127) << 3;

    // ---- stage everything once ----
    for (int i = t; i < 64 * 67; i += 256) S.w1[(i / 67) * 68 + (i % 67)] = W1[i];
    if (t < 64) { S.w1[t * 68 + 67] = 0.0f; S.b1s[t] = b1[t]; S.b2s[t] = b2[t]; }
    if (t < 128) S.b3s[t] = b3[t];
    for (int i = t; i < 64 * 64; i += 256) S.w2[i] = W2[i];
    for (int i = t; i < 128 * 64; i += 256) S.w3[i] = W3[i];
    if (t < 24)
        S.cxyz[t / 3][t % 3] = new_xyz[((size_t)b * NPOINT + p0 + t / 3) * 3 + (t % 3)];
    __syncthreads();

    // ---- ball query: wave wv handles local centers 2wv, 2wv+1 ----
    const int wv = t >> 6, lane = t & 63;
    const float* pts = xyz + (size_t)b * NPTS * 3;
    for (int q = 0; q < 2; ++q) {
        const int ci = wv * 2 + q;
        const float cx = S.cxyz[ci][0];
        const float cy = S.cxyz[ci][1];
        const float cz = S.cxyz[ci][2];
        int hits = 0, first = 0;
        for (int j0 = 0; j0 < NPTS; j0 += 64) {
            const int j = j0 + lane;
            float x = pts[3 * j], y = pts[3 * j + 1], z = pts[3 * j + 2];
            float dx = __fsub_rn(x, cx), dy = __fsub_rn(y, cy), dz = __fsub_rn(z, cz);
            float d2 = __fadd_rn(__fadd_rn(__fmul_rn(dx, dx), __fmul_rn(dy, dy)),
                                 __fmul_rn(dz, dz));
            const bool pred = d2 < R2;
            const unsigned long long mask = __ballot(pred);
            if (hits == 0 && mask)
                first = j0 + (int)(__ffsll((unsigned long long)mask) - 1);
            if (pred) {
                int slot = hits + (int)__popcll(mask & ((1ull << lane) - 1ull));
                if (slot < NSAMPLE) S.gidx[ci][slot] = j;
            }
            hits += (int)__popcll(mask);
            if (hits >= NSAMPLE) break;
        }
        if (hits < NSAMPLE && lane >= hits && lane < NSAMPLE)
            S.gidx[ci][lane] = first;
    }
    __syncthreads();

    // ---- MLP: 32 threads per center; weights from LDS (float4 rows) ----
    const int ci = t >> 5, s = t & 31;
    const int p  = p0 + ci;
    const int gi = S.gidx[ci][s];
    const float nx0 = S.cxyz[ci][0];
    const float nx1 = S.cxyz[ci][1];
    const float nx2 = S.cxyz[ci][2];
    const float* pp = xyz + ((size_t)b * NPTS + gi) * 3;
    float h[68];
    h[0] = pp[0] - nx0;
    h[1] = pp[1] - nx1;
    h[2] = pp[2] - nx2;
    const float4* fp = (const float4*)(feat_t + ((size_t)b * NPTS + gi) * NCH);
#pragma unroll
    for (int qq = 0; qq < 16; ++qq) {
        float4 v = fp[qq];
        h[3 + 4 * qq] = v.x; h[4 + 4 * qq] = v.y;
        h[5 + 4 * qq] = v.z; h[6 + 4 * qq] = v.w;
    }
    h[67] = 0.0f;

    float h1[64];
#pragma unroll
    for (int o = 0; o < 64; ++o) {
        const float4* wr = (const float4*)(&S.w1[o * 68]);
        float a0 = 0.f, a1 = 0.f, a2 = 0.f, a3 = 0.f;
#pragma unroll
        for (int qq = 0; qq < 17; ++qq) {
            float4 w = wr[qq];
            a0 = fmaf(w.x, h[4 * qq + 0], a0);
            a1 = fmaf(w.y, h[4 * qq + 1], a1);
            a2 = fmaf(w.z, h[4 * qq + 2], a2);
            a3 = fmaf(w.w, h[4 * qq + 3], a3);
        }
        h1[o] = fmaxf((a0 + a1) + (a2 + a3) + S.b1s[o], 0.0f);
    }

    float h2[64];
#pragma unroll
    for (int o = 0; o < 64; ++o) {
        const float4* wr = (const float4*)(&S.w2[o * 64]);
        float a0 = 0.f, a1 = 0.f, a2 = 0.f, a3 = 0.f;
#pragma unroll
        for (int qq = 0; qq < 16; ++qq) {
            float4 w = wr[qq];
            a0 = fmaf(w.x, h1[4 * qq + 0], a0);
            a1 = fmaf(w.y, h1[4 * qq + 1], a1);
            a2 = fmaf(w.z, h1[4 * qq + 2], a2);
            a3 = fmaf(w.w, h1[4 * qq + 3], a3);
        }
        h2[o] = fmaxf((a0 + a1) + (a2 + a3) + S.b2s[o], 0.0f);
    }

    float* outp = out_feat + ((size_t)b * 128) * NPOINT + p;
#pragma unroll
    for (int o = 0; o < 128; ++o) {
        const float4* wr = (const float4*)(&S.w3[o * 64]);
        float a0 = 0.f, a1 = 0.f, a2 = 0.f, a3 = 0.f;
#pragma unroll
        for (int qq = 0; qq < 16; ++qq) {
            float4 w = wr[qq];
            a0 = fmaf(w.x, h2[4 * qq + 0], a0);
            a1 = fmaf(w.y, h2[4 * qq + 1], a1);
            a2 = fmaf(w.z, h2[4 * qq + 2], a2);
            a3 = fmaf(w.w, h2[4 * qq + 3], a3);
        }
        float acc = fmaxf((a0 + a1) + (a2 + a3) + S.b3s[o], 0.0f);
#pragma unroll
        for (int m = 1; m < 32; m <<= 1) acc = fmaxf(acc, __shfl_xor(acc, m, 64));
        if (s == 0) outp[(size_t)o * NPOINT] = acc;
    }
}

extern "C" void kernel_launch(void* const* d_in, const int* in_sizes, int n_in,
                              void* d_out, int out_size, void* d_ws, size_t ws_size,
                              hipStream_t stream) {
    const float* xyz  = (const float*)d_in[0];
    const float* feat = (const float*)d_in[1];
    const float* W1   = (const float*)d_in[2];
    const float* b1   = (const float*)d_in[3];
    const float* W2   = (const float*)d_in[4];
    const float* b2   = (const float*)d_in[5];
    const float* W3   = (const float*)d_in[6];
    const float* b3   = (const float*)d_in[7];

    float* new_xyz  = (float*)d_out;                                  // (B, NPOINT, 3)
    float* out_feat = (float*)d_out + (size_t)BATCH * NPOINT * 3;     // (B, 128, NPOINT)

    float* feat_t = (float*)d_ws;                                     // (B, NPTS, NCH)

    hipLaunchKernelGGL(fps_tr_kernel, dim3(BATCH + BATCH * (NPTS / 64)), dim3(256), 0,
                       stream, xyz, new_xyz, feat, feat_t);
    hipLaunchKernelGGL(bq_mlp_kernel, dim3(BATCH * NPOINT / 8), dim3(256), 0, stream,
                       xyz, feat_t, new_xyz,
                       W1, b1, W2, b2, W3, b3, out_feat);
}